// Round 1
// baseline (809.452 us; speedup 1.0000x reference)
//
#include <hip/hip_runtime.h>
#include <math.h>

#define N_NODES 20000
#define N_EDGES 160000
#define NODE_DIM 64
#define EDGE_DIM 16
#define H 32
#define STEPS 3

// ---------------------------------------------------------------------------
// Kernel 1: h = node_feat @ W_np.T + b_np      [N,64]@[64,32] -> [N,32]
// thread per (v,i); 32 consecutive threads share one node row (broadcast).
// ---------------------------------------------------------------------------
__global__ void node_proj_kernel(const float* __restrict__ nf,
                                 const float* __restrict__ W,
                                 const float* __restrict__ b,
                                 float* __restrict__ h) {
    int tid = blockIdx.x * blockDim.x + threadIdx.x;
    if (tid >= N_NODES * H) return;
    int v = tid >> 5;
    int i = tid & 31;
    const float* __restrict__ row = nf + v * NODE_DIM;
    const float* __restrict__ w   = W + i * NODE_DIM;
    float acc = b[i];
#pragma unroll
    for (int d = 0; d < NODE_DIM; ++d) acc = fmaf(row[d], w[d], acc);
    h[tid] = acc;
}

// ---------------------------------------------------------------------------
// Kernel 2: per-edge message + scatter-add.
// msg[e,i] = sum_k (b_e[i*32+k] + sum_d W_e[(i*32+k)*16+d]*ef[e,d]) * h[src,k]
// 32 lanes per edge (lane = i). W_e staged in LDS transposed to [(k*16+d)][i]
// so lane-consecutive LDS reads are bank-conflict-free. b_e rows held in
// 32 registers per lane. h_src / ef distributed via shfl (width 32).
// 64 KB LDS -> 2 blocks/CU.
// ---------------------------------------------------------------------------
#define EDGES_PER_BLK 8   // 256 threads = 8 groups of 32

__global__ __launch_bounds__(256, 2)
void edge_msg_kernel(const int* __restrict__ ei,
                     const float* __restrict__ ef,
                     const float* __restrict__ We,
                     const float* __restrict__ be,
                     const float* __restrict__ h,
                     float* __restrict__ m) {
    __shared__ float Ws[H * H * EDGE_DIM];   // [(k*16+d)*32 + i] : 64 KB

    // cooperative load + transpose of W_e (source idx = (i*32+k)*16+d)
    for (int idx = threadIdx.x; idx < H * H * EDGE_DIM; idx += blockDim.x) {
        int i = idx >> 9;
        int k = (idx >> 4) & 31;
        int d = idx & 15;
        Ws[(k * EDGE_DIM + d) * H + i] = We[idx];
    }
    __syncthreads();

    int lane = threadIdx.x & 31;
    int grp  = threadIdx.x >> 5;

    // per-lane bias row: bval[k] = b_e[lane*32 + k]
    float bval[H];
#pragma unroll
    for (int k = 0; k < H; ++k) bval[k] = be[lane * H + k];

    for (int e0 = blockIdx.x * EDGES_PER_BLK; e0 < N_EDGES;
         e0 += gridDim.x * EDGES_PER_BLK) {
        int e = e0 + grp;
        if (e < N_EDGES) {
            int src = ei[e];
            int dst = ei[N_EDGES + e];
            float hval  = h[src * H + lane];
            float efval = (lane < EDGE_DIM) ? ef[e * EDGE_DIM + lane] : 0.f;

            float efr[EDGE_DIM];
#pragma unroll
            for (int d = 0; d < EDGE_DIM; ++d) efr[d] = __shfl(efval, d, 32);

            float msg = 0.f;
#pragma unroll
            for (int k = 0; k < H; ++k) {
                float hk = __shfl(hval, k, 32);
                float a  = bval[k];
#pragma unroll
                for (int d = 0; d < EDGE_DIM; ++d)
                    a = fmaf(Ws[(k * EDGE_DIM + d) * H + lane], efr[d], a);
                msg = fmaf(a, hk, msg);
            }
            atomicAdd(&m[dst * H + lane], msg);
        }
    }
}

// ---------------------------------------------------------------------------
// Kernel 3: GRU cell. 32 lanes per node (lane = hidden index i).
// W_ih / W_hh staged in LDS transposed to [k][row] (row = gate*32 + i) so
// lane-consecutive reads are conflict-free. m/h rows distributed via shfl.
// ---------------------------------------------------------------------------
__global__ __launch_bounds__(256)
void gru_kernel(const float* __restrict__ Wih,
                const float* __restrict__ Whh,
                const float* __restrict__ bih,
                const float* __restrict__ bhh,
                const float* __restrict__ m,
                const float* __restrict__ h,
                float* __restrict__ hout) {
    __shared__ float WihT[H * 3 * H];   // [k*96 + row] : 12 KB
    __shared__ float WhhT[H * 3 * H];   // 12 KB
    for (int idx = threadIdx.x; idx < 3 * H * H; idx += blockDim.x) {
        int row = idx >> 5;   // src idx = row*32 + k
        int k   = idx & 31;
        WihT[k * (3 * H) + row] = Wih[idx];
        WhhT[k * (3 * H) + row] = Whh[idx];
    }
    __syncthreads();

    int lane = threadIdx.x & 31;
    int grp  = threadIdx.x >> 5;

    for (int v0 = blockIdx.x * 8; v0 < N_NODES; v0 += gridDim.x * 8) {
        int v = v0 + grp;
        if (v < N_NODES) {
            float mv = m[v * H + lane];
            float hv = h[v * H + lane];
            float ir = bih[lane], iz = bih[H + lane], in_ = bih[2 * H + lane];
            float hr = bhh[lane], hz = bhh[H + lane], hn  = bhh[2 * H + lane];
#pragma unroll
            for (int k = 0; k < H; ++k) {
                float mk = __shfl(mv, k, 32);
                float hk = __shfl(hv, k, 32);
                ir  = fmaf(WihT[k * 96 + lane],          mk, ir);
                iz  = fmaf(WihT[k * 96 + H + lane],      mk, iz);
                in_ = fmaf(WihT[k * 96 + 2 * H + lane],  mk, in_);
                hr  = fmaf(WhhT[k * 96 + lane],          hk, hr);
                hz  = fmaf(WhhT[k * 96 + H + lane],      hk, hz);
                hn  = fmaf(WhhT[k * 96 + 2 * H + lane],  hk, hn);
            }
            float r  = 1.f / (1.f + __expf(-(ir + hr)));
            float z  = 1.f / (1.f + __expf(-(iz + hz)));
            float nn = tanhf(in_ + r * hn);
            hout[v * H + lane] = (1.f - z) * nn + z * hv;
        }
    }
}

// ---------------------------------------------------------------------------
extern "C" void kernel_launch(void* const* d_in, const int* in_sizes, int n_in,
                              void* d_out, int out_size, void* d_ws, size_t ws_size,
                              hipStream_t stream) {
    const float* node_feat = (const float*)d_in[0];
    const int*   edge_idx  = (const int*)  d_in[1];
    const float* edge_feat = (const float*)d_in[2];
    const float* W_np      = (const float*)d_in[3];
    const float* b_np      = (const float*)d_in[4];
    const float* W_e       = (const float*)d_in[5];
    const float* b_e       = (const float*)d_in[6];
    const float* W_ih      = (const float*)d_in[7];
    const float* W_hh      = (const float*)d_in[8];
    const float* b_ih      = (const float*)d_in[9];
    const float* b_hh      = (const float*)d_in[10];

    float* h = (float*)d_ws;                    // N*H
    float* m = h + N_NODES * H;                 // N*H
    float* out = (float*)d_out;

    // h0 = node_feat @ W_np.T + b_np
    node_proj_kernel<<<(N_NODES * H + 255) / 256, 256, 0, stream>>>(
        node_feat, W_np, b_np, h);

    for (int step = 0; step < STEPS; ++step) {
        hipMemsetAsync(m, 0, (size_t)N_NODES * H * sizeof(float), stream);
        edge_msg_kernel<<<512, 256, 0, stream>>>(edge_idx, edge_feat, W_e, b_e,
                                                 h, m);
        float* dst_h = (step == STEPS - 1) ? out : h;
        gru_kernel<<<256, 256, 0, stream>>>(W_ih, W_hh, b_ih, b_hh, m, h, dst_h);
    }
}

// Round 2
// 499.817 us; speedup vs baseline: 1.6195x; 1.6195x over previous
//
#include <hip/hip_runtime.h>
#include <math.h>

#define N_NODES 20000
#define N_EDGES 160000
#define NODE_DIM 64
#define EDGE_DIM 16
#define H 32
#define STEPS 3
#define UCOLS (H * EDGE_DIM)   // 512 columns: c = i*16 + d

// ---------------------------------------------------------------------------
// Kernel 1: h = node_feat @ W_np.T + b_np      [N,64]@[64,32] -> [N,32]
// ---------------------------------------------------------------------------
__global__ void node_proj_kernel(const float* __restrict__ nf,
                                 const float* __restrict__ W,
                                 const float* __restrict__ b,
                                 float* __restrict__ h) {
    int tid = blockIdx.x * blockDim.x + threadIdx.x;
    if (tid >= N_NODES * H) return;
    int v = tid >> 5;
    int i = tid & 31;
    const float* __restrict__ row = nf + v * NODE_DIM;
    const float* __restrict__ w   = W + i * NODE_DIM;
    float acc = b[i];
#pragma unroll
    for (int d = 0; d < NODE_DIM; ++d) acc = fmaf(row[d], w[d], acc);
    h[tid] = acc;
}

// ---------------------------------------------------------------------------
// Kernel 2: per-node precompute
//   U[v, i*16+d] = sum_k W_e[(i*32+k)*16+d] * h[v,k]
//   Bh[v, i]     = sum_k b_e[i*32+k] * h[v,k]
// W_e staged in LDS as W2t[k*512 + (i*16+d)] (64 KB) so lane i reads its 16
// contiguous floats with 4x ds_read_b128. b_e staged transposed (4 KB).
// 32-lane group per node; h row distributed via shfl. Persistent grid so the
// LDS fill is amortized over ~39 nodes per group.
// ---------------------------------------------------------------------------
__global__ __launch_bounds__(256, 2)
void u_precompute_kernel(const float* __restrict__ We,
                         const float* __restrict__ be,
                         const float* __restrict__ h,
                         float* __restrict__ U,
                         float* __restrict__ Bh) {
    __shared__ float W2t[H * UCOLS];   // [k*512 + i*16 + d] : 64 KB
    __shared__ float bet[H * H];       // [k*32 + i]         : 4 KB

    // stage W_e transposed: src idx = (i*32+k)*16 + d  ->  W2t[k*512 + i*16 + d]
    for (int idx = threadIdx.x; idx < H * H * EDGE_DIM; idx += blockDim.x) {
        int i = idx >> 9;
        int k = (idx >> 4) & 31;
        int d = idx & 15;
        W2t[k * UCOLS + i * EDGE_DIM + d] = We[idx];
    }
    // stage b_e transposed: bet[k*32+i] = be[i*32+k]  (write banks consecutive)
    for (int idx = threadIdx.x; idx < H * H; idx += blockDim.x) {
        int i = idx & 31;
        int k = idx >> 5;
        bet[k * H + i] = be[i * H + k];
    }
    __syncthreads();

    int lane = threadIdx.x & 31;
    int grp  = threadIdx.x >> 5;

    for (int v0 = blockIdx.x * 8; v0 < N_NODES; v0 += gridDim.x * 8) {
        int v = v0 + grp;
        if (v >= N_NODES) continue;
        float hval = h[v * H + lane];

        float4 acc0 = {0.f, 0.f, 0.f, 0.f};
        float4 acc1 = {0.f, 0.f, 0.f, 0.f};
        float4 acc2 = {0.f, 0.f, 0.f, 0.f};
        float4 acc3 = {0.f, 0.f, 0.f, 0.f};
        float  bacc = 0.f;

        const float4* __restrict__ Wrow =
            (const float4*)(W2t + lane * EDGE_DIM);   // lane's 4 float4 per k
#pragma unroll
        for (int k = 0; k < H; ++k) {
            float hk = __shfl(hval, k, 32);
            float4 w0 = Wrow[k * (UCOLS / 4) + 0];
            float4 w1 = Wrow[k * (UCOLS / 4) + 1];
            float4 w2 = Wrow[k * (UCOLS / 4) + 2];
            float4 w3 = Wrow[k * (UCOLS / 4) + 3];
            acc0.x = fmaf(w0.x, hk, acc0.x); acc0.y = fmaf(w0.y, hk, acc0.y);
            acc0.z = fmaf(w0.z, hk, acc0.z); acc0.w = fmaf(w0.w, hk, acc0.w);
            acc1.x = fmaf(w1.x, hk, acc1.x); acc1.y = fmaf(w1.y, hk, acc1.y);
            acc1.z = fmaf(w1.z, hk, acc1.z); acc1.w = fmaf(w1.w, hk, acc1.w);
            acc2.x = fmaf(w2.x, hk, acc2.x); acc2.y = fmaf(w2.y, hk, acc2.y);
            acc2.z = fmaf(w2.z, hk, acc2.z); acc2.w = fmaf(w2.w, hk, acc2.w);
            acc3.x = fmaf(w3.x, hk, acc3.x); acc3.y = fmaf(w3.y, hk, acc3.y);
            acc3.z = fmaf(w3.z, hk, acc3.z); acc3.w = fmaf(w3.w, hk, acc3.w);
            bacc   = fmaf(bet[k * H + lane], hk, bacc);
        }
        float4* __restrict__ Urow = (float4*)(U + (size_t)v * UCOLS + lane * EDGE_DIM);
        Urow[0] = acc0; Urow[1] = acc1; Urow[2] = acc2; Urow[3] = acc3;
        Bh[v * H + lane] = bacc;
    }
}

// ---------------------------------------------------------------------------
// Kernel 3: edge gather + tiny dot + scatter-add.
//   msg[e,i] = Bh[src,i] + sum_d ef[e,d] * U[src, i*16+d]
// 32 lanes per edge (lane = i). Lane reads its 16 U floats as 4x float4
// (group covers a contiguous 2 KB row). ef distributed via shfl.
// ---------------------------------------------------------------------------
__global__ __launch_bounds__(256)
void edge_msg_kernel(const int* __restrict__ ei,
                     const float* __restrict__ ef,
                     const float* __restrict__ U,
                     const float* __restrict__ Bh,
                     float* __restrict__ m) {
    int tid  = blockIdx.x * blockDim.x + threadIdx.x;
    int e    = tid >> 5;
    int lane = tid & 31;
    if (e >= N_EDGES) return;

    int src = ei[e];
    int dst = ei[N_EDGES + e];

    float efv = (lane < EDGE_DIM) ? ef[e * EDGE_DIM + lane] : 0.f;

    const float4* __restrict__ Urow =
        (const float4*)(U + (size_t)src * UCOLS + lane * EDGE_DIM);
    float4 u0 = Urow[0];
    float4 u1 = Urow[1];
    float4 u2 = Urow[2];
    float4 u3 = Urow[3];

    float msg = Bh[src * H + lane];
    msg = fmaf(__shfl(efv,  0, 32), u0.x, msg);
    msg = fmaf(__shfl(efv,  1, 32), u0.y, msg);
    msg = fmaf(__shfl(efv,  2, 32), u0.z, msg);
    msg = fmaf(__shfl(efv,  3, 32), u0.w, msg);
    msg = fmaf(__shfl(efv,  4, 32), u1.x, msg);
    msg = fmaf(__shfl(efv,  5, 32), u1.y, msg);
    msg = fmaf(__shfl(efv,  6, 32), u1.z, msg);
    msg = fmaf(__shfl(efv,  7, 32), u1.w, msg);
    msg = fmaf(__shfl(efv,  8, 32), u2.x, msg);
    msg = fmaf(__shfl(efv,  9, 32), u2.y, msg);
    msg = fmaf(__shfl(efv, 10, 32), u2.z, msg);
    msg = fmaf(__shfl(efv, 11, 32), u2.w, msg);
    msg = fmaf(__shfl(efv, 12, 32), u3.x, msg);
    msg = fmaf(__shfl(efv, 13, 32), u3.y, msg);
    msg = fmaf(__shfl(efv, 14, 32), u3.z, msg);
    msg = fmaf(__shfl(efv, 15, 32), u3.w, msg);

    atomicAdd(&m[dst * H + lane], msg);
}

// ---------------------------------------------------------------------------
// Kernel 4: GRU cell (unchanged from R1).
// ---------------------------------------------------------------------------
__global__ __launch_bounds__(256)
void gru_kernel(const float* __restrict__ Wih,
                const float* __restrict__ Whh,
                const float* __restrict__ bih,
                const float* __restrict__ bhh,
                const float* __restrict__ m,
                const float* __restrict__ h,
                float* __restrict__ hout) {
    __shared__ float WihT[H * 3 * H];
    __shared__ float WhhT[H * 3 * H];
    for (int idx = threadIdx.x; idx < 3 * H * H; idx += blockDim.x) {
        int row = idx >> 5;
        int k   = idx & 31;
        WihT[k * (3 * H) + row] = Wih[idx];
        WhhT[k * (3 * H) + row] = Whh[idx];
    }
    __syncthreads();

    int lane = threadIdx.x & 31;
    int grp  = threadIdx.x >> 5;

    for (int v0 = blockIdx.x * 8; v0 < N_NODES; v0 += gridDim.x * 8) {
        int v = v0 + grp;
        if (v < N_NODES) {
            float mv = m[v * H + lane];
            float hv = h[v * H + lane];
            float ir = bih[lane], iz = bih[H + lane], in_ = bih[2 * H + lane];
            float hr = bhh[lane], hz = bhh[H + lane], hn  = bhh[2 * H + lane];
#pragma unroll
            for (int k = 0; k < H; ++k) {
                float mk = __shfl(mv, k, 32);
                float hk = __shfl(hv, k, 32);
                ir  = fmaf(WihT[k * 96 + lane],          mk, ir);
                iz  = fmaf(WihT[k * 96 + H + lane],      mk, iz);
                in_ = fmaf(WihT[k * 96 + 2 * H + lane],  mk, in_);
                hr  = fmaf(WhhT[k * 96 + lane],          hk, hr);
                hz  = fmaf(WhhT[k * 96 + H + lane],      hk, hz);
                hn  = fmaf(WhhT[k * 96 + 2 * H + lane],  hk, hn);
            }
            float r  = 1.f / (1.f + __expf(-(ir + hr)));
            float z  = 1.f / (1.f + __expf(-(iz + hz)));
            float nn = tanhf(in_ + r * hn);
            hout[v * H + lane] = (1.f - z) * nn + z * hv;
        }
    }
}

// ---------------------------------------------------------------------------
extern "C" void kernel_launch(void* const* d_in, const int* in_sizes, int n_in,
                              void* d_out, int out_size, void* d_ws, size_t ws_size,
                              hipStream_t stream) {
    const float* node_feat = (const float*)d_in[0];
    const int*   edge_idx  = (const int*)  d_in[1];
    const float* edge_feat = (const float*)d_in[2];
    const float* W_np      = (const float*)d_in[3];
    const float* b_np      = (const float*)d_in[4];
    const float* W_e       = (const float*)d_in[5];
    const float* b_e       = (const float*)d_in[6];
    const float* W_ih      = (const float*)d_in[7];
    const float* W_hh      = (const float*)d_in[8];
    const float* b_ih      = (const float*)d_in[9];
    const float* b_hh      = (const float*)d_in[10];

    float* h  = (float*)d_ws;                      // N*H
    float* m  = h  + N_NODES * H;                  // N*H
    float* Bh = m  + N_NODES * H;                  // N*H
    float* U  = Bh + N_NODES * H;                  // N*512 (41 MB)
    float* out = (float*)d_out;

    node_proj_kernel<<<(N_NODES * H + 255) / 256, 256, 0, stream>>>(
        node_feat, W_np, b_np, h);

    for (int step = 0; step < STEPS; ++step) {
        u_precompute_kernel<<<512, 256, 0, stream>>>(W_e, b_e, h, U, Bh);
        hipMemsetAsync(m, 0, (size_t)N_NODES * H * sizeof(float), stream);
        edge_msg_kernel<<<(N_EDGES * H + 255) / 256, 256, 0, stream>>>(
            edge_idx, edge_feat, U, Bh, m);
        float* dst_h = (step == STEPS - 1) ? out : h;
        gru_kernel<<<256, 256, 0, stream>>>(W_ih, W_hh, b_ih, b_hh, m, h, dst_h);
    }
}